// Round 7
// baseline (267.403 us; speedup 1.0000x reference)
//
#include <hip/hip_runtime.h>
#include <cstdint>
#include <cstddef>

typedef short bf16x8 __attribute__((ext_vector_type(8)));
typedef float f32x4 __attribute__((ext_vector_type(4)));

#define DM 1024
#define NHEADS 16
#define NGROUPS 4
#define DK 64
#define BATCH 2
#define SEQ 2048
#define MROWS 4096

#define QB_ELEMS   ((size_t)BATCH*NHEADS*SEQ*DK)   // 4M shorts
#define KB_ELEMS   ((size_t)BATCH*NGROUPS*SEQ*DK)  // 1M
#define VT_ELEMS   KB_ELEMS                        // 1M  ([b][g][d][col] permuted)
#define XC_ELEMS   ((size_t)MROWS*DM)              // 4M  (xbf, later reused as ctx)
#define WQKV_ELEMS ((size_t)1536*DM)
#define WO_ELEMS   ((size_t)DM*DM)

#define SCL_Q 0.180336880f    // (1/sqrt(64)) * log2(e), folded into Q

__device__ __forceinline__ ushort f2bf(float f) {          // RNE
    union { float f; uint32_t u; } a; a.f = f;
    uint32_t u = a.u;
    return (ushort)((u + 0x7FFFu + ((u >> 16) & 1u)) >> 16);
}

// 64x64 fp32->bf16 transpose tile through LDS (tl must be float[64][65])
__device__ __forceinline__ void transpose_tile(
        const float* __restrict__ src, int src_ld, ushort* __restrict__ dst,
        int r0, int c0, int tid, float (*tl)[65])
{
    const int rr = tid >> 4, cc = (tid & 15) * 4;
#pragma unroll
    for (int p = 0; p < 4; p++) {
        int r = rr + p * 16;
        float4 v = *(const float4*)(src + (size_t)(r0 + r) * src_ld + c0 + cc);
        tl[cc + 0][r] = v.x; tl[cc + 1][r] = v.y;
        tl[cc + 2][r] = v.z; tl[cc + 3][r] = v.w;
    }
    __syncthreads();
#pragma unroll
    for (int p = 0; p < 4; p++) {
        int c = rr + p * 16;
        ushort4 o;
        o.x = f2bf(tl[c][cc + 0]); o.y = f2bf(tl[c][cc + 1]);
        o.z = f2bf(tl[c][cc + 2]); o.w = f2bf(tl[c][cc + 3]);
        *(ushort4*)(dst + (size_t)(c0 + c) * 1024 + r0 + cc) = o;
    }
}

// ---------------------------------------------------------------------------
// Prep (641 blocks): W_Q/W_K/W_V transposes -> WqkvT, x fp32->bf16, bias.
// (W_O transpose rides inside the QKV GEMM launch.)
// ---------------------------------------------------------------------------
__global__ __launch_bounds__(256) void gqa_prep_kernel(
        const float* __restrict__ x,
        const float* __restrict__ WQ, const float* __restrict__ WK,
        const float* __restrict__ WV,
        const float* __restrict__ bQ, const float* __restrict__ bK,
        const float* __restrict__ bV,
        ushort* __restrict__ xbf, ushort* __restrict__ WqkvT,
        float* __restrict__ bcat)
{
    __shared__ float tl[64][65];
    const int bid = blockIdx.x, tid = threadIdx.x;
    if (bid < 256) {            // WQ [d][c] -> WqkvT rows c
        transpose_tile(WQ, 1024, WqkvT, (bid >> 4) * 64, (bid & 15) * 64, tid, tl);
    } else if (bid < 320) {     // WK[g] [d][k] -> rows 1024+g*64
        int t = bid - 256, g = t >> 4;
        transpose_tile(WK + (size_t)g * 1024 * 64, 64,
                       WqkvT + (size_t)(1024 + g * 64) * 1024,
                       (t & 15) * 64, 0, tid, tl);
    } else if (bid < 384) {     // WV[g] -> rows 1280+g*64
        int t = bid - 320, g = t >> 4;
        transpose_tile(WV + (size_t)g * 1024 * 64, 64,
                       WqkvT + (size_t)(1280 + g * 64) * 1024,
                       (t & 15) * 64, 0, tid, tl);
    } else if (bid < 640) {     // x convert
        int cid = bid - 384;
        const float* xs = x + (size_t)cid * 16384;
        ushort* xd = xbf + (size_t)cid * 16384;
#pragma unroll
        for (int p = 0; p < 16; p++) {
            float4 v = *(const float4*)(xs + p * 1024 + tid * 4);
            ushort4 o = { f2bf(v.x), f2bf(v.y), f2bf(v.z), f2bf(v.w) };
            *(ushort4*)(xd + p * 1024 + tid * 4) = o;
        }
    } else {
        for (int i = tid; i < 1536; i += 256) {
            float v = (i < 1024) ? bQ[i] : (i < 1280 ? bK[i - 1024] : bV[i - 1280]);
            bcat[i] = v;
        }
    }
}

// ---------------------------------------------------------------------------
// GEMM, no LDS: each WAVE owns a 64x64 tile, fragments loaded directly
// global->VGPR (perfectly coalesced: 16 lanes x 64B segments). BK=32,
// register ping-pong (load kt+1 while MFMA kt) -> compiler emits fine
// vmcnt(N), no barriers at all. XCD swizzle pins A row-panels to one L2.
// QKV_EPI: scatter Q (pre-scaled), K, permuted V^T. Riders (QKV launch
// only): first 256 blocks transpose W_O -> WoT.
// ---------------------------------------------------------------------------
template<bool QKV_EPI>
__global__ __launch_bounds__(256, 2) void gqa_gemm_kernel(
        const ushort* __restrict__ A, const ushort* __restrict__ BT,
        const float* __restrict__ bias, float* __restrict__ outF,
        ushort* __restrict__ Qb, ushort* __restrict__ Kb, ushort* __restrict__ Vtg,
        const float* __restrict__ WO, ushort* __restrict__ WoT)
{
    const int tid = threadIdx.x;
    int blk = blockIdx.x;

    if constexpr (QKV_EPI) {
        if (blk < 256) {   // W_O transpose rider
            __shared__ float tl[64][65];
            transpose_tile(WO, 1024, WoT, (blk >> 4) * 64, (blk & 15) * 64, tid, tl);
            return;
        }
        blk -= 256;
    }

    const int wave = tid >> 6, lane = tid & 63;
    const int lr = lane & 15, lq = lane >> 4;
    const int xcd = blk & 7, sb = blk >> 3;
    const int bm = xcd * 8 + (sb & 7);            // A panel pinned to one XCD
    const int bn = (sb >> 3) * 4 + wave;

    const ushort* aRow[4]; const ushort* bRow[4];
#pragma unroll
    for (int i = 0; i < 4; i++)
        aRow[i] = A  + (size_t)(bm * 64 + i * 16 + lr) * 1024 + lq * 8;
#pragma unroll
    for (int j = 0; j < 4; j++)
        bRow[j] = BT + (size_t)(bn * 64 + j * 16 + lr) * 1024 + lq * 8;

    f32x4 acc[4][4];
#pragma unroll
    for (int i = 0; i < 4; i++)
#pragma unroll
        for (int j = 0; j < 4; j++) acc[i][j] = (f32x4){0.f, 0.f, 0.f, 0.f};

    bf16x8 a0[4], b0[4], a1[4], b1[4];
#pragma unroll
    for (int i = 0; i < 4; i++) a0[i] = *(const bf16x8*)(aRow[i]);
#pragma unroll
    for (int j = 0; j < 4; j++) b0[j] = *(const bf16x8*)(bRow[j]);

    for (int kt = 0; kt < 32; kt += 2) {
        // prefetch kt+1 into buf1
#pragma unroll
        for (int i = 0; i < 4; i++) a1[i] = *(const bf16x8*)(aRow[i] + (kt + 1) * 32);
#pragma unroll
        for (int j = 0; j < 4; j++) b1[j] = *(const bf16x8*)(bRow[j] + (kt + 1) * 32);
        // compute kt (buf0)
#pragma unroll
        for (int i = 0; i < 4; i++)
#pragma unroll
            for (int j = 0; j < 4; j++)
                acc[i][j] = __builtin_amdgcn_mfma_f32_16x16x32_bf16(a0[i], b0[j], acc[i][j], 0, 0, 0);
        // prefetch kt+2 into buf0
        if (kt + 2 < 32) {
#pragma unroll
            for (int i = 0; i < 4; i++) a0[i] = *(const bf16x8*)(aRow[i] + (kt + 2) * 32);
#pragma unroll
            for (int j = 0; j < 4; j++) b0[j] = *(const bf16x8*)(bRow[j] + (kt + 2) * 32);
        }
        // compute kt+1 (buf1)
#pragma unroll
        for (int i = 0; i < 4; i++)
#pragma unroll
            for (int j = 0; j < 4; j++)
                acc[i][j] = __builtin_amdgcn_mfma_f32_16x16x32_bf16(a1[i], b1[j], acc[i][j], 0, 0, 0);
    }

#pragma unroll
    for (int i = 0; i < 4; i++) {
        int mg = bm * 64 + i * 16 + lq * 4;
        int b = mg >> 11, s = mg & 2047;
#pragma unroll
        for (int j = 0; j < 4; j++) {
            int cg = bn * 64 + j * 16 + lr;
            float bv = bias[cg];
            if constexpr (QKV_EPI) {
                int d = cg & 63;
                if (cg < 1024) {
                    int h = cg >> 6;
                    ushort* dst = Qb + ((size_t)(b * NHEADS + h) * SEQ + s) * DK + d;
#pragma unroll
                    for (int r = 0; r < 4; r++)
                        dst[r * DK] = f2bf((acc[i][j][r] + bv) * SCL_Q);
                } else if (cg < 1280) {
                    int g = (cg - 1024) >> 6;
                    ushort* dst = Kb + ((size_t)(b * NGROUPS + g) * SEQ + s) * DK + d;
#pragma unroll
                    for (int r = 0; r < 4; r++) dst[r * DK] = f2bf(acc[i][j][r] + bv);
                } else {
                    int g = (cg - 1280) >> 6;
                    // permuted V^T column: 4-key group kg -> position (kg&3)*2+(kg>>2)
                    int s4 = s >> 2, kg = s4 & 7;
                    int col = ((s4 >> 3) << 5) + (((((kg & 3) << 1) | (kg >> 2))) << 2);
                    ushort4 pk;
                    pk.x = f2bf(acc[i][j][0] + bv); pk.y = f2bf(acc[i][j][1] + bv);
                    pk.z = f2bf(acc[i][j][2] + bv); pk.w = f2bf(acc[i][j][3] + bv);
                    *(ushort4*)(Vtg + ((size_t)(b * NGROUPS + g) * DK + d) * SEQ + col) = pk;
                }
            } else {
#pragma unroll
                for (int r = 0; r < 4; r++)
                    outF[(size_t)(mg + r) * DM + cg] = acc[i][j][r] + bv;
            }
        }
    }
}

// ---------------------------------------------------------------------------
// Attention, no LDS, no barriers: 1024 fully independent waves. Each wave =
// 64 q-rows of one head, sweeping all 2048 keys in 32-key iters with direct
// global->VGPR K / permuted-V^T fragment loads (coalesced 64B segments,
// XCD-pinned L2). S^T = K·Q^T; P packed in-register as a K=32 B-frag
// (v_perm truncation); PV accumulates O^T; row-sums on VALU + 2 shuffles.
// Register ping-pong hides L2 latency under the 32-MFMA shadow.
// ---------------------------------------------------------------------------
__global__ __launch_bounds__(256, 2) void gqa_attn_kernel(
        const ushort* __restrict__ Qb, const ushort* __restrict__ Kb,
        const ushort* __restrict__ Vtg, ushort* __restrict__ ctx)
{
    const int tid = threadIdx.x, wave = tid >> 6, lane = tid & 63;
    const int lr = lane & 15, lq = lane >> 4;
    const int blk = blockIdx.x;
    const int bg = blk & 7;                    // (b,g) pinned per XCD
    const int r = (blk >> 3) * 4 + wave;       // 0..127
    const int b = bg >> 2, g = bg & 3;
    const int h = r & 3, qt = r >> 2;          // 4 heads/group, 32 q-tiles
    const int hg = g * 4 + h;
    const int s0 = qt * 64;

    const ushort* Qh = Qb  + (size_t)(b * NHEADS  + hg) * SEQ * DK;
    const ushort* Kg = Kb  + (size_t)(b * NGROUPS + g)  * SEQ * DK;
    const ushort* Vg = Vtg + (size_t)(b * NGROUPS + g)  * DK * SEQ;

    bf16x8 qf[4][2];
#pragma unroll
    for (int qs = 0; qs < 4; qs++)
#pragma unroll
        for (int kh = 0; kh < 2; kh++)
            qf[qs][kh] = *(const bf16x8*)(Qh + (size_t)(s0 + qs * 16 + lr) * DK + kh * 32 + lq * 8);

    const ushort* kB[2][2]; const ushort* vB[4];
#pragma unroll
    for (int nt = 0; nt < 2; nt++)
#pragma unroll
        for (int kh = 0; kh < 2; kh++)
            kB[nt][kh] = Kg + (size_t)(nt * 16 + lr) * DK + (kh * 4 + lq) * 8;
#pragma unroll
    for (int j = 0; j < 4; j++)
        vB[j] = Vg + (size_t)(j * 16 + lr) * SEQ + lq * 8;

    f32x4 of[4][4];
#pragma unroll
    for (int qs = 0; qs < 4; qs++)
#pragma unroll
        for (int j = 0; j < 4; j++) of[qs][j] = (f32x4){0.f, 0.f, 0.f, 0.f};
    float lsum[4] = {0.f, 0.f, 0.f, 0.f};

    bf16x8 kf0[2][2], vf0[4], kf1[2][2], vf1[4];

    auto ldkv = [&](bf16x8 kf[2][2], bf16x8 vf[4], int it) {
        const int ko = it * 32 * DK;   // 32 K-rows per iter
        const int vo = it * 32;        // 32 V^T columns per iter
#pragma unroll
        for (int nt = 0; nt < 2; nt++)
#pragma unroll
            for (int kh = 0; kh < 2; kh++)
                kf[nt][kh] = *(const bf16x8*)(kB[nt][kh] + ko);
#pragma unroll
        for (int j = 0; j < 4; j++)
            vf[j] = *(const bf16x8*)(vB[j] + vo);
    };

    auto step = [&](bf16x8 kf[2][2], bf16x8 vf[4]) {
        f32x4 sc[4][2];
#pragma unroll
        for (int qs = 0; qs < 4; qs++)
#pragma unroll
            for (int nt = 0; nt < 2; nt++) {
                f32x4 s = (f32x4){0.f, 0.f, 0.f, 0.f};
                s = __builtin_amdgcn_mfma_f32_16x16x32_bf16(kf[nt][0], qf[qs][0], s, 0, 0, 0);
                s = __builtin_amdgcn_mfma_f32_16x16x32_bf16(kf[nt][1], qf[qs][1], s, 0, 0, 0);
                sc[qs][nt] = s;
            }
        union PF { bf16x8 v; uint32_t w[4]; };
        PF pf[4];
#pragma unroll
        for (int qs = 0; qs < 4; qs++) {
#pragma unroll
            for (int nt = 0; nt < 2; nt++) {
                union { float f; uint32_t u; } e0, e1, e2, e3;
                e0.f = __builtin_amdgcn_exp2f(sc[qs][nt][0]);
                e1.f = __builtin_amdgcn_exp2f(sc[qs][nt][1]);
                e2.f = __builtin_amdgcn_exp2f(sc[qs][nt][2]);
                e3.f = __builtin_amdgcn_exp2f(sc[qs][nt][3]);
                lsum[qs] += (e0.f + e1.f) + (e2.f + e3.f);
                pf[qs].w[nt * 2 + 0] = __builtin_amdgcn_perm(e1.u, e0.u, 0x07060302u);
                pf[qs].w[nt * 2 + 1] = __builtin_amdgcn_perm(e3.u, e2.u, 0x07060302u);
            }
        }
#pragma unroll
        for (int qs = 0; qs < 4; qs++)
#pragma unroll
            for (int j = 0; j < 4; j++)
                of[qs][j] = __builtin_amdgcn_mfma_f32_16x16x32_bf16(vf[j], pf[qs].v, of[qs][j], 0, 0, 0);
    };

    ldkv(kf0, vf0, 0);
    for (int it = 0; it < 64; it += 2) {
        ldkv(kf1, vf1, it + 1);
        step(kf0, vf0);
        if (it + 2 < 64) ldkv(kf0, vf0, it + 2);
        step(kf1, vf1);
    }

    // row-sum: lanes sharing q=lr are lq=0..3 -> xor 16, 32
    float inv[4];
#pragma unroll
    for (int qs = 0; qs < 4; qs++) {
        float v = lsum[qs];
        v += __shfl_xor(v, 16);
        v += __shfl_xor(v, 32);
        inv[qs] = 1.0f / v;
    }
    ushort* cbp = ctx + (size_t)b * SEQ * DM;
#pragma unroll
    for (int qs = 0; qs < 4; qs++) {
        int s = s0 + qs * 16 + lr;
#pragma unroll
        for (int j = 0; j < 4; j++) {
            ushort4 o;
            o.x = f2bf(of[qs][j][0] * inv[qs]);
            o.y = f2bf(of[qs][j][1] * inv[qs]);
            o.z = f2bf(of[qs][j][2] * inv[qs]);
            o.w = f2bf(of[qs][j][3] * inv[qs]);
            *(ushort4*)(cbp + (size_t)s * DM + hg * 64 + j * 16 + lq * 4) = o;
        }
    }
}

// ---------------------------------------------------------------------------
extern "C" void kernel_launch(void* const* d_in, const int* in_sizes, int n_in,
                              void* d_out, int out_size, void* d_ws, size_t ws_size,
                              hipStream_t stream) {
    const float* x  = (const float*)d_in[0];
    const float* WQ = (const float*)d_in[1];
    const float* bQ = (const float*)d_in[2];
    const float* WK = (const float*)d_in[3];
    const float* bK = (const float*)d_in[4];
    const float* WV = (const float*)d_in[5];
    const float* bV = (const float*)d_in[6];
    const float* WO = (const float*)d_in[7];
    const float* bO = (const float*)d_in[8];

    ushort* Qb    = (ushort*)d_ws;
    ushort* Kb    = Qb + QB_ELEMS;
    ushort* Vtg   = Kb + KB_ELEMS;
    ushort* xc    = Vtg + VT_ELEMS;       // xbf (QKV input), later reused as ctx
    ushort* WqkvT = xc + XC_ELEMS;
    ushort* WoT   = WqkvT + WQKV_ELEMS;
    float*  bcat  = (float*)(WoT + WO_ELEMS);

    gqa_prep_kernel<<<641, 256, 0, stream>>>(x, WQ, WK, WV, bQ, bK, bV,
                                             xc, WqkvT, bcat);
    // 256 rider blocks (W_O transpose) + 384 GEMM blocks (1536 waves)
    gqa_gemm_kernel<true><<<640, 256, 0, stream>>>(
        xc, WqkvT, bcat, nullptr, Qb, Kb, Vtg, WO, WoT);
    gqa_attn_kernel<<<256, 256, 0, stream>>>(Qb, Kb, Vtg, xc);
    // 256 GEMM blocks (1024 waves)
    gqa_gemm_kernel<false><<<256, 256, 0, stream>>>(
        xc, WoT, bO, (float*)d_out, nullptr, nullptr, nullptr, nullptr, nullptr);
}

// Round 8
// 159.125 us; speedup vs baseline: 1.6805x; 1.6805x over previous
//
#include <hip/hip_runtime.h>
#include <cstdint>
#include <cstddef>

typedef short bf16x8 __attribute__((ext_vector_type(8)));
typedef float f32x4 __attribute__((ext_vector_type(4)));

#define DM 1024
#define NHEADS 16
#define NGROUPS 4
#define DK 64
#define BATCH 2
#define SEQ 2048
#define MROWS 4096

#define QB_ELEMS   ((size_t)BATCH*NHEADS*SEQ*DK)   // 4M shorts
#define KB_ELEMS   ((size_t)BATCH*NGROUPS*SEQ*DK)  // 1M
#define VT_ELEMS   KB_ELEMS                        // 1M  ([b][g][d][col] permuted)
#define XC_ELEMS   ((size_t)MROWS*DM)              // 4M  (xbf, later reused as ctx)
#define WQKV_ELEMS ((size_t)1536*DM)
#define WO_ELEMS   ((size_t)DM*DM)

#define SCL_Q 0.180336880f    // (1/sqrt(64)) * log2(e), folded into Q

__device__ __forceinline__ ushort f2bf(float f) {          // RNE
    union { float f; uint32_t u; } a; a.f = f;
    uint32_t u = a.u;
    return (ushort)((u + 0x7FFFu + ((u >> 16) & 1u)) >> 16);
}

// async global->LDS, 16B/lane; LDS dest = wave-uniform base + lane*16
__device__ __forceinline__ void gll16(const void* g, void* l) {
    __builtin_amdgcn_global_load_lds((const __attribute__((address_space(1))) void*)g,
                                     (__attribute__((address_space(3))) void*)l, 16, 0, 0);
}

// 64x64 fp32->bf16 transpose tile through LDS (tl must be float[64][65])
__device__ __forceinline__ void transpose_tile(
        const float* __restrict__ src, int src_ld, ushort* __restrict__ dst,
        int r0, int c0, int tid, float (*tl)[65])
{
    const int rr = tid >> 4, cc = (tid & 15) * 4;
#pragma unroll
    for (int p = 0; p < 4; p++) {
        int r = rr + p * 16;
        float4 v = *(const float4*)(src + (size_t)(r0 + r) * src_ld + c0 + cc);
        tl[cc + 0][r] = v.x; tl[cc + 1][r] = v.y;
        tl[cc + 2][r] = v.z; tl[cc + 3][r] = v.w;
    }
    __syncthreads();
#pragma unroll
    for (int p = 0; p < 4; p++) {
        int c = rr + p * 16;
        ushort4 o;
        o.x = f2bf(tl[c][cc + 0]); o.y = f2bf(tl[c][cc + 1]);
        o.z = f2bf(tl[c][cc + 2]); o.w = f2bf(tl[c][cc + 3]);
        *(ushort4*)(dst + (size_t)(c0 + c) * 1024 + r0 + cc) = o;
    }
}

// ---------------------------------------------------------------------------
// Prep (641 blocks): W_Q/W_K/W_V transposes -> WqkvT, x fp32->bf16, bias.
// (W_O transpose rides inside the QKV GEMM launch.)
// ---------------------------------------------------------------------------
__global__ __launch_bounds__(256) void gqa_prep_kernel(
        const float* __restrict__ x,
        const float* __restrict__ WQ, const float* __restrict__ WK,
        const float* __restrict__ WV,
        const float* __restrict__ bQ, const float* __restrict__ bK,
        const float* __restrict__ bV,
        ushort* __restrict__ xbf, ushort* __restrict__ WqkvT,
        float* __restrict__ bcat)
{
    __shared__ float tl[64][65];
    const int bid = blockIdx.x, tid = threadIdx.x;
    if (bid < 256) {            // WQ [d][c] -> WqkvT rows c
        transpose_tile(WQ, 1024, WqkvT, (bid >> 4) * 64, (bid & 15) * 64, tid, tl);
    } else if (bid < 320) {     // WK[g] [d][k] -> rows 1024+g*64
        int t = bid - 256, g = t >> 4;
        transpose_tile(WK + (size_t)g * 1024 * 64, 64,
                       WqkvT + (size_t)(1024 + g * 64) * 1024,
                       (t & 15) * 64, 0, tid, tl);
    } else if (bid < 384) {     // WV[g] -> rows 1280+g*64
        int t = bid - 320, g = t >> 4;
        transpose_tile(WV + (size_t)g * 1024 * 64, 64,
                       WqkvT + (size_t)(1280 + g * 64) * 1024,
                       (t & 15) * 64, 0, tid, tl);
    } else if (bid < 640) {     // x convert
        int cid = bid - 384;
        const float* xs = x + (size_t)cid * 16384;
        ushort* xd = xbf + (size_t)cid * 16384;
#pragma unroll
        for (int p = 0; p < 16; p++) {
            float4 v = *(const float4*)(xs + p * 1024 + tid * 4);
            ushort4 o = { f2bf(v.x), f2bf(v.y), f2bf(v.z), f2bf(v.w) };
            *(ushort4*)(xd + p * 1024 + tid * 4) = o;
        }
    } else {
        for (int i = tid; i < 1536; i += 256) {
            float v = (i < 1024) ? bQ[i] : (i < 1280 ? bK[i - 1024] : bV[i - 1280]);
            bcat[i] = v;
        }
    }
}

// ---------------------------------------------------------------------------
// GEMM (R6, best-known): C[4096][N] = A[4096][1024]*B (+bias), BT[N][1024].
// Tile 64x64, BK=64, 4 waves (2x2, wave 32x32), gll16 dbuf, 1 barrier/iter.
// 32 KB LDS, launch_bounds(256,4). RIDERS: first 256 blocks transpose W_O.
// ---------------------------------------------------------------------------
template<bool QKV_EPI, int BN, bool RIDERS>
__global__ __launch_bounds__(256, 4) void gqa_gemm_kernel(
        const ushort* __restrict__ A, const ushort* __restrict__ BT,
        const float* __restrict__ bias, float* __restrict__ outF,
        ushort* __restrict__ Qb, ushort* __restrict__ Kb, ushort* __restrict__ Vtg,
        const float* __restrict__ WO, ushort* __restrict__ WoT)
{
    __shared__ ushort smem[4][4096];     // As buf0/1, Bs buf0/1 (32 KB)
    const int tid = threadIdx.x;
    int i = blockIdx.x;

    if constexpr (RIDERS) {
        if (i < 256) {   // W_O transpose rider
            float (*tl)[65] = (float(*)[65])&smem[0][0];
            transpose_tile(WO, 1024, WoT, (i >> 4) * 64, (i & 15) * 64, tid, tl);
            return;
        }
        i -= 256;
    }

    const int xcd = i & 7, slot = i >> 3;
    const int bm = (slot / BN) * 8 + xcd;
    const int bn = slot % BN;
    const int wave = tid >> 6, lane = tid & 63;
    const int wm = (wave & 1) * 32, wn = (wave >> 1) * 32;
    const int lr = lane & 15, lq = lane >> 4;
    const int swz = lr & 7;

    const ushort* srcA[2]; const ushort* srcB[2]; int dstOff[2];
#pragma unroll
    for (int p = 0; p < 2; p++) {
        int slt = p * 256 + tid;
        int row = slt >> 3, cb = (slt & 7) ^ (row & 7);
        srcA[p] = A  + (size_t)(bm * 64 + row) * 1024 + cb * 8;
        srcB[p] = BT + (size_t)(bn * 64 + row) * 1024 + cb * 8;
        dstOff[p] = p * 2048 + wave * 512;
    }

    f32x4 acc[2][2];
#pragma unroll
    for (int ii = 0; ii < 2; ii++)
#pragma unroll
        for (int j = 0; j < 2; j++) acc[ii][j] = (f32x4){0.f, 0.f, 0.f, 0.f};

#pragma unroll
    for (int p = 0; p < 2; p++) {
        gll16(srcA[p], &smem[0][dstOff[p]]);
        gll16(srcB[p], &smem[2][dstOff[p]]);
    }

    for (int kt = 0; kt < 16; kt++) {
        __syncthreads();
        if (kt < 15) {
            int buf = (kt + 1) & 1, ko = (kt + 1) * 64;
#pragma unroll
            for (int p = 0; p < 2; p++) {
                gll16(srcA[p] + ko, &smem[buf][dstOff[p]]);
                gll16(srcB[p] + ko, &smem[2 + buf][dstOff[p]]);
            }
        }
        const ushort* as = smem[kt & 1];
        const ushort* bs = smem[2 + (kt & 1)];
        bf16x8 af[2][2], bfr[2][2];
#pragma unroll
        for (int kh = 0; kh < 2; kh++) {
#pragma unroll
            for (int ii = 0; ii < 2; ii++)
                af[kh][ii] = *(const bf16x8*)&as[(wm + ii * 16 + lr) * 64 + ((kh * 4 + lq) ^ swz) * 8];
#pragma unroll
            for (int j = 0; j < 2; j++)
                bfr[kh][j] = *(const bf16x8*)&bs[(wn + j * 16 + lr) * 64 + ((kh * 4 + lq) ^ swz) * 8];
        }
#pragma unroll
        for (int kh = 0; kh < 2; kh++)
#pragma unroll
            for (int ii = 0; ii < 2; ii++)
#pragma unroll
                for (int j = 0; j < 2; j++)
                    acc[ii][j] = __builtin_amdgcn_mfma_f32_16x16x32_bf16(af[kh][ii], bfr[kh][j], acc[ii][j], 0, 0, 0);
    }

#pragma unroll
    for (int ii = 0; ii < 2; ii++) {
        int mg = bm * 64 + wm + ii * 16 + lq * 4;
        int b = mg >> 11, s = mg & 2047;
#pragma unroll
        for (int j = 0; j < 2; j++) {
            int cg = bn * 64 + wn + j * 16 + lr;
            float bv = bias[cg];
            if constexpr (QKV_EPI) {
                int d = cg & 63;
                if (cg < 1024) {
                    int h = cg >> 6;
                    ushort* dst = Qb + ((size_t)(b * NHEADS + h) * SEQ + s) * DK + d;
#pragma unroll
                    for (int r = 0; r < 4; r++)
                        dst[r * DK] = f2bf((acc[ii][j][r] + bv) * SCL_Q);
                } else if (cg < 1280) {
                    int g = (cg - 1024) >> 6;
                    ushort* dst = Kb + ((size_t)(b * NGROUPS + g) * SEQ + s) * DK + d;
#pragma unroll
                    for (int r = 0; r < 4; r++) dst[r * DK] = f2bf(acc[ii][j][r] + bv);
                } else {
                    int g = (cg - 1280) >> 6;
                    // permuted V^T column: 4-key group kg -> position (kg&3)*2+(kg>>2)
                    int s4 = s >> 2, kg = s4 & 7;
                    int col = ((s4 >> 3) << 5) + (((((kg & 3) << 1) | (kg >> 2))) << 2);
                    ushort4 pk;
                    pk.x = f2bf(acc[ii][j][0] + bv); pk.y = f2bf(acc[ii][j][1] + bv);
                    pk.z = f2bf(acc[ii][j][2] + bv); pk.w = f2bf(acc[ii][j][3] + bv);
                    *(ushort4*)(Vtg + ((size_t)(b * NGROUPS + g) * DK + d) * SEQ + col) = pk;
                }
            } else {
#pragma unroll
                for (int r = 0; r < 4; r++)
                    outF[(size_t)(mg + r) * DM + cg] = acc[ii][j][r] + bv;
            }
        }
    }
}

// ---------------------------------------------------------------------------
// Attention: 512 blocks, XCD-local (bg = i&7). Block = 128 q x full key
// sweep in 128-key tiles (16 iters). 4 waves 2x2: (wq = q-half 64, wt =
// t-half 64). Per wave-iter: 32 S-MFMA + 32 PV-MFMA + 8 sum-MFMA, 16 b128.
// S^T = K·Q^T; P packed in-register (v_perm truncation) as K=32 B-frags vs
// column-permuted V^T. t-halves combined at the end via LDS overlay.
// LDS 64 KB dbuf (K 128x64, V^T 64x128), 2 blocks/CU.
// ---------------------------------------------------------------------------
__global__ __launch_bounds__(256, 2) void gqa_attn_kernel(
        const ushort* __restrict__ Qb, const ushort* __restrict__ Kb,
        const ushort* __restrict__ Vtg, ushort* __restrict__ ctx)
{
    __shared__ ushort Ks[2][128 * 64];   // 32 KB
    __shared__ ushort Vs[2][64 * 128];   // 32 KB

    const int tid = threadIdx.x, wave = tid >> 6, lane = tid & 63;
    const int lr = lane & 15, lq = lane >> 4;
    const int swz = lr & 7;
    const int wq = wave & 1, wt = wave >> 1;
    const int i = blockIdx.x;
    const int bg = i & 7, s2 = i >> 3;
    const int qt = s2 & 15, h = s2 >> 4;
    const int b = bg >> 2, g = bg & 3, hg = g * 4 + h;

    const ushort* Qh = Qb  + (size_t)(b * NHEADS  + hg) * SEQ * DK;
    const ushort* Kg = Kb  + (size_t)(b * NGROUPS + g)  * SEQ * DK;
    const ushort* Vg = Vtg + (size_t)(b * NGROUPS + g)  * DK * SEQ;

    const int s0 = qt * 128 + wq * 64;
    const int tb = wt * 64;              // wave's t-stripe base within tile

    bf16x8 qf[4][2];
#pragma unroll
    for (int qs = 0; qs < 4; qs++)
#pragma unroll
        for (int kh = 0; kh < 2; kh++)
            qf[qs][kh] = *(const bf16x8*)(Qh + (size_t)(s0 + qs * 16 + lr) * DK + kh * 32 + lq * 8);

    // staging: K 4 slots (row = slot>>3 in 0..127, 8 chunks/row);
    //          V 4 slots (row = slot>>4 in 0..63, 16 chunks/row, XOR low-3)
    const ushort* srcK[4]; const ushort* srcV[4]; int dstOff[4];
#pragma unroll
    for (int p = 0; p < 4; p++) {
        int slt = p * 256 + tid;
        int krow = slt >> 3, kcb = (slt & 7) ^ (krow & 7);
        srcK[p] = Kg + (size_t)krow * DK + kcb * 8;
        int vrow = slt >> 4, vc = slt & 15;
        int vcb = (vc & 8) | ((vc ^ vrow) & 7);
        srcV[p] = Vg + (size_t)vrow * SEQ + vcb * 8;
        dstOff[p] = (p * 256 + wave * 64) * 8;   // ushort offset; lane*8 added by HW
    }

    f32x4 of[4][4];
#pragma unroll
    for (int qs = 0; qs < 4; qs++)
#pragma unroll
        for (int j = 0; j < 4; j++) of[qs][j] = (f32x4){0.f, 0.f, 0.f, 0.f};
    f32x4 accL[4];
#pragma unroll
    for (int qs = 0; qs < 4; qs++) accL[qs] = (f32x4){0.f, 0.f, 0.f, 0.f};

    bf16x8 ones;
#pragma unroll
    for (int k = 0; k < 8; k++) ones[k] = (short)0x3F80;

#pragma unroll
    for (int p = 0; p < 4; p++) {
        gll16(srcK[p], &Ks[0][dstOff[p]]);
        gll16(srcV[p], &Vs[0][dstOff[p]]);
    }

    for (int it = 0; it < 16; it++) {
        __syncthreads();
        if (it < 15) {
            int buf = (it + 1) & 1, t0 = (it + 1) * 128;
#pragma unroll
            for (int p = 0; p < 4; p++) {
                gll16(srcK[p] + (size_t)t0 * DK, &Ks[buf][dstOff[p]]);
                gll16(srcV[p] + t0, &Vs[buf][dstOff[p]]);
            }
        }
        const ushort* ks = Ks[it & 1];
        const ushort* vs = Vs[it & 1];

        bf16x8 kf[4][2];
#pragma unroll
        for (int nt = 0; nt < 4; nt++)
#pragma unroll
            for (int kh = 0; kh < 2; kh++)
                kf[nt][kh] = *(const bf16x8*)&ks[(tb + nt * 16 + lr) * 64 + ((kh * 4 + lq) ^ swz) * 8];

        bf16x8 vf[4][2];
#pragma unroll
        for (int j = 0; j < 4; j++)
#pragma unroll
            for (int kk = 0; kk < 2; kk++)
                vf[j][kk] = *(const bf16x8*)&vs[(j * 16 + lr) * 128 + (wt * 8 + ((kk * 4 + lq) ^ swz)) * 8];

        // S^T[t][q] over the wave's 64-t stripe (Q pre-scaled -> log2 domain)
        f32x4 sc[4][4];
#pragma unroll
        for (int qs = 0; qs < 4; qs++)
#pragma unroll
            for (int nt = 0; nt < 4; nt++) {
                f32x4 s = (f32x4){0.f, 0.f, 0.f, 0.f};
                s = __builtin_amdgcn_mfma_f32_16x16x32_bf16(kf[nt][0], qf[qs][0], s, 0, 0, 0);
                s = __builtin_amdgcn_mfma_f32_16x16x32_bf16(kf[nt][1], qf[qs][1], s, 0, 0, 0);
                sc[qs][nt] = s;
            }

        // exp2 -> truncate-pack into two K=32 B-frags per qs; sums via ones-MFMA
        union PF { bf16x8 v; uint32_t w[4]; };
        PF pf[4][2];
#pragma unroll
        for (int qs = 0; qs < 4; qs++) {
#pragma unroll
            for (int nt = 0; nt < 4; nt++) {
                union { float f; uint32_t u; } e0, e1, e2, e3;
                e0.f = __builtin_amdgcn_exp2f(sc[qs][nt][0]);
                e1.f = __builtin_amdgcn_exp2f(sc[qs][nt][1]);
                e2.f = __builtin_amdgcn_exp2f(sc[qs][nt][2]);
                e3.f = __builtin_amdgcn_exp2f(sc[qs][nt][3]);
                pf[qs][nt >> 1].w[(nt & 1) * 2 + 0] = __builtin_amdgcn_perm(e1.u, e0.u, 0x07060302u);
                pf[qs][nt >> 1].w[(nt & 1) * 2 + 1] = __builtin_amdgcn_perm(e3.u, e2.u, 0x07060302u);
            }
            accL[qs] = __builtin_amdgcn_mfma_f32_16x16x32_bf16(ones, pf[qs][0].v, accL[qs], 0, 0, 0);
            accL[qs] = __builtin_amdgcn_mfma_f32_16x16x32_bf16(ones, pf[qs][1].v, accL[qs], 0, 0, 0);
        }

        // O^T[d][q] += V^T(stripe) · P
#pragma unroll
        for (int qs = 0; qs < 4; qs++)
#pragma unroll
            for (int j = 0; j < 4; j++) {
                of[qs][j] = __builtin_amdgcn_mfma_f32_16x16x32_bf16(vf[j][0], pf[qs][0].v, of[qs][j], 0, 0, 0);
                of[qs][j] = __builtin_amdgcn_mfma_f32_16x16x32_bf16(vf[j][1], pf[qs][1].v, of[qs][j], 0, 0, 0);
            }
    }

    // ---- combine t-halves (wt=1 -> LDS overlay -> wt=0 adds) ----
    __syncthreads();                       // all staging reads done; overlay safe
    float* comb = (float*)&Ks[0][0];       // 32 KB: [wq][(qs*4+j)*256 + lane*4]
    float* accX = (float*)&Vs[0][0];       // [ (wq*4+qs)*16 + lr ]
    if (wt == 1) {
        float* cw = comb + wq * 4096;
#pragma unroll
        for (int qs = 0; qs < 4; qs++)
#pragma unroll
            for (int j = 0; j < 4; j++)
                *(f32x4*)&cw[(qs * 4 + j) * 256 + lane * 4] = of[qs][j];
        if (lq == 0) {
#pragma unroll
            for (int qs = 0; qs < 4; qs++) accX[(wq * 4 + qs) * 16 + lr] = accL[qs][0];
        }
    }
    __syncthreads();
    if (wt == 0) {
        const float* cw = comb + wq * 4096;
        float inv[4];
#pragma unroll
        for (int qs = 0; qs < 4; qs++)
            inv[qs] = 1.0f / (accL[qs][0] + accX[(wq * 4 + qs) * 16 + lr]);
        ushort* cbp = ctx + (size_t)b * SEQ * DM;
#pragma unroll
        for (int qs = 0; qs < 4; qs++) {
            int s = s0 + qs * 16 + lr;
#pragma unroll
            for (int j = 0; j < 4; j++) {
                f32x4 o2 = of[qs][j] + *(const f32x4*)&cw[(qs * 4 + j) * 256 + lane * 4];
                ushort4 o;
                o.x = f2bf(o2[0] * inv[qs]);
                o.y = f2bf(o2[1] * inv[qs]);
                o.z = f2bf(o2[2] * inv[qs]);
                o.w = f2bf(o2[3] * inv[qs]);
                *(ushort4*)(cbp + (size_t)s * DM + hg * 64 + j * 16 + lq * 4) = o;
            }
        }
    }
}

// ---------------------------------------------------------------------------
extern "C" void kernel_launch(void* const* d_in, const int* in_sizes, int n_in,
                              void* d_out, int out_size, void* d_ws, size_t ws_size,
                              hipStream_t stream) {
    const float* x  = (const float*)d_in[0];
    const float* WQ = (const float*)d_in[1];
    const float* bQ = (const float*)d_in[2];
    const float* WK = (const float*)d_in[3];
    const float* bK = (const float*)d_in[4];
    const float* WV = (const float*)d_in[5];
    const float* bV = (const float*)d_in[6];
    const float* WO = (const float*)d_in[7];
    const float* bO = (const float*)d_in[8];

    ushort* Qb    = (ushort*)d_ws;
    ushort* Kb    = Qb + QB_ELEMS;
    ushort* Vtg   = Kb + KB_ELEMS;
    ushort* xc    = Vtg + VT_ELEMS;       // xbf (QKV input), later reused as ctx
    ushort* WqkvT = xc + XC_ELEMS;
    ushort* WoT   = WqkvT + WQKV_ELEMS;
    float*  bcat  = (float*)(WoT + WO_ELEMS);

    gqa_prep_kernel<<<641, 256, 0, stream>>>(x, WQ, WK, WV, bQ, bK, bV,
                                             xc, WqkvT, bcat);
    gqa_gemm_kernel<true, 24, true><<<1792, 256, 0, stream>>>(
        xc, WqkvT, bcat, nullptr, Qb, Kb, Vtg, WO, WoT);
    gqa_attn_kernel<<<512, 256, 0, stream>>>(Qb, Kb, Vtg, xc);
    gqa_gemm_kernel<false, 16, false><<<1024, 256, 0, stream>>>(
        xc, WoT, bO, (float*)d_out, nullptr, nullptr, nullptr, nullptr, nullptr);
}